// Round 9
// baseline (331.510 us; speedup 1.0000x reference)
//
#include <hip/hip_runtime.h>

// SNN direction decoder — single fused kernel: in-LDS f32->f16 hi/lo split +
// MFMA GEMM + LIF scan + FC2.  B=256, T=100, I=512, H=1024, C=8.
// fp32 GEMM as 3-term f16 GEMM: xh*wh + xh*wl + xl*wh (scaled 2^6 / 2^-12).
// W pre-split [wh|wl] (2 MB ws, L2-resident); x split inside snn_one at
// LDS-write time with coalesced loads. R9: A k-tile kt+1 prefetched into a
// register double-buffer right after barrier-1, overlapping B's L2 fetch and
// the A-convert VALU -> staging serial cost ~1200 -> ~500 cyc per k-tile.

#define B_   256
#define T_   100
#define I_   512
#define H_   1024
#define C_   8
#define M_   (B_ * T_)        // 25600
#define SC   64.0f            // 2^6 pre-scale
#define ISC  (1.0f / 4096.0f) // 2^-12 epilogue un-scale
#define CP   132              // Cs row pitch (floats)

typedef _Float16 half8 __attribute__((ext_vector_type(8)));
typedef __fp16 fp16x2 __attribute__((ext_vector_type(2)));  // pkrtz native type
typedef float floatx4 __attribute__((ext_vector_type(4)));

__device__ __forceinline__ void ld_g2l(const _Float16* g, _Float16* l) {
    __builtin_amdgcn_global_load_lds(
        (const __attribute__((address_space(1))) void*)g,
        (__attribute__((address_space(3))) void*)l, 16, 0, 0);
}

__device__ __forceinline__ half8 pk_hi(float4 f0, float4 f1) {
    fp16x2 p0 = __builtin_amdgcn_cvt_pkrtz(f0.x * SC, f0.y * SC);
    fp16x2 p1 = __builtin_amdgcn_cvt_pkrtz(f0.z * SC, f0.w * SC);
    fp16x2 p2 = __builtin_amdgcn_cvt_pkrtz(f1.x * SC, f1.y * SC);
    fp16x2 p3 = __builtin_amdgcn_cvt_pkrtz(f1.z * SC, f1.w * SC);
    half8 h;
    h[0] = (_Float16)p0[0]; h[1] = (_Float16)p0[1];
    h[2] = (_Float16)p1[0]; h[3] = (_Float16)p1[1];
    h[4] = (_Float16)p2[0]; h[5] = (_Float16)p2[1];
    h[6] = (_Float16)p3[0]; h[7] = (_Float16)p3[1];
    return h;
}

// W1[H][512] fp32 -> Wsp[H][wh(512)|wl(512)] f16; also logits init.
__global__ void __launch_bounds__(256)
split_w(const float* __restrict__ W1, const float* __restrict__ b2,
        _Float16* __restrict__ Wsp, float* __restrict__ out) {
    int g = blockIdx.x * 256 + threadIdx.x;   // H_*64 threads
    if (g < B_ * C_) out[g] = 100.0f * b2[g & (C_ - 1)];
    int h = g >> 6;
    int i0 = (g & 63) * 8;
    const float* src = W1 + (size_t)h * I_ + i0;
    float4 v0 = *(const float4*)(src);
    float4 v1 = *(const float4*)(src + 4);
    float vv[8] = {v0.x, v0.y, v0.z, v0.w, v1.x, v1.y, v1.z, v1.w};
    half8 hi = pk_hi(v0, v1);
    half8 lo;
#pragma unroll
    for (int j = 0; j < 8; ++j)
        lo[j] = (_Float16)(vv[j] * SC - (float)hi[j]);
    _Float16* r = Wsp + (size_t)h * 1024 + i0;
    *(half8*)(r) = hi;
    *(half8*)(r + 512) = lo;
}

// Fused everything. XCD-swizzled: xcd=blk&7 owns batches [32*xcd, 32*xcd+32).
__global__ void __launch_bounds__(256, 2)
snn_one(const float* __restrict__ x, const _Float16* __restrict__ Wsp,
        const float* __restrict__ b1, const float* __restrict__ W2,
        float* __restrict__ logits) {
    __shared__ union {
        struct {
            __align__(16) _Float16 Ah[128 * 64];
            __align__(16) _Float16 Al[128 * 64];
            __align__(16) _Float16 Bh[128 * 64];
            __align__(16) _Float16 Bl[128 * 64];
        } g;
        float Cs[64 * CP];
    } sm;
    const int tid = threadIdx.x;
    const int lane = tid & 63;
    const int w = tid >> 6;

    const int xcd = blockIdx.x & 7;
    const int jj = blockIdx.x >> 3;        // 0..255 per-XCD sequence
    const int b  = xcd * 32 + (jj >> 3);   // batch 0..255
    const int n0 = (jj & 7) * 128;         // h tile offset

    const int wm = (w >> 1) * 64;   // wave's 64x64 sub-tile
    const int wn = (w & 1) * 64;
    const int srow = lane >> 3;
    const int sc16 = (lane & 7) ^ srow;    // XOR swizzle (matches read side)
    const int quad = lane >> 4;
    const int l15 = lane & 15;
    const int l7 = lane & 7;

    // --- B staging (async g2l): wave w stages rows [32w,32w+32), 4 x 8 rows
    const _Float16* bg[4];
    _Float16* blh[4];
    _Float16* bll[4];
#pragma unroll
    for (int j = 0; j < 4; ++j) {
        const int r = w * 32 + j * 8 + srow;
        bg[j]  = Wsp + (size_t)(n0 + r) * 1024 + sc16 * 8;
        blh[j] = &sm.g.Bh[(w * 32 + j * 8) * 64];
        bll[j] = &sm.g.Bl[(w * 32 + j * 8) * 64];
    }

    // --- A staging (manual, coalesced): 2 threads/row, 32 contiguous f32 each
    const int arow = tid >> 1;             // tile row 0..127
    const int ac0 = (tid & 1) * 32;        // col offset within k-tile
    int ar = b * T_ + arow;                // global m row (garbage masked later)
    if (ar >= M_) ar = M_ - 1;             // clamp: no OOB on last batch
    const float* axp = x + (size_t)ar * I_ + ac0;
    const bool astage = (arow < 112);      // rows 112..127 never read (fr3 skip)
    int aoff[4];                           // swizzled LDS f16 offsets
#pragma unroll
    for (int q = 0; q < 4; ++q) {
        const int k16 = (tid & 1) * 4 + q;
        aoff[q] = arow * 64 + ((k16 ^ (arow & 7)) * 8);
    }

    floatx4 acc[4][4];
#pragma unroll
    for (int i = 0; i < 4; ++i)
#pragma unroll
        for (int q = 0; q < 4; ++q) acc[i][q] = (floatx4){0.f, 0.f, 0.f, 0.f};

    // --- A register double-buffer: preload kt=0
    float4 fA[2][8];
    if (astage) {
#pragma unroll
        for (int q = 0; q < 8; ++q) fA[0][q] = *(const float4*)(axp + q * 4);
    }

    for (int kt = 0; kt < 8; ++kt) {
        const int ko = kt * 64;
        const int cb = kt & 1;             // current A reg-buffer
        __syncthreads();
#pragma unroll
        for (int j = 0; j < 4; ++j) {
            ld_g2l(bg[j] + ko, blh[j]);          // wh tile
            ld_g2l(bg[j] + 512 + ko, bll[j]);    // wl tile
        }
        if (astage) {
            // prefetch next k-tile into the other reg-buffer (overlaps convert)
            const int kon = (kt < 7) ? ko + 64 : ko;
#pragma unroll
            for (int q = 0; q < 8; ++q)
                fA[cb ^ 1][q] = *(const float4*)(axp + kon + q * 4);
            // convert current buffer -> LDS
#pragma unroll
            for (int q = 0; q < 4; ++q) {
                float4 g0 = fA[cb][2 * q], g1 = fA[cb][2 * q + 1];
                float vv[8] = {g0.x, g0.y, g0.z, g0.w, g1.x, g1.y, g1.z, g1.w};
                half8 hi = pk_hi(g0, g1);
                half8 lo;
#pragma unroll
                for (int e = 0; e < 8; ++e)
                    lo[e] = (_Float16)(vv[e] * SC - (float)hi[e]);
                *(half8*)&sm.g.Ah[aoff[q]] = hi;
                *(half8*)&sm.g.Al[aoff[q]] = lo;
            }
        }
        __syncthreads();
#pragma unroll
        for (int ks = 0; ks < 2; ++ks) {
            const int phys = ((ks * 4 + quad) ^ l7) * 8;
            half8 avh[4], avl[4];
#pragma unroll
            for (int fr = 0; fr < 4; ++fr) {
                if (fr < 3 || wm == 0) {
                    const int ro = (wm + fr * 16 + l15) * 64 + phys;
                    avh[fr] = *(const half8*)&sm.g.Ah[ro];
                    avl[fr] = *(const half8*)&sm.g.Al[ro];
                }
            }
#pragma unroll
            for (int fn = 0; fn < 4; ++fn) {
                const int ro = (wn + fn * 16 + l15) * 64 + phys;
                half8 bvh = *(const half8*)&sm.g.Bh[ro];
                half8 bvl = *(const half8*)&sm.g.Bl[ro];
#pragma unroll
                for (int fr = 0; fr < 4; ++fr) {
                    if (fr < 3 || wm == 0) {
                        acc[fr][fn] = __builtin_amdgcn_mfma_f32_16x16x32_f16(
                            avh[fr], bvh, acc[fr][fn], 0, 0, 0);
                        acc[fr][fn] = __builtin_amdgcn_mfma_f32_16x16x32_f16(
                            avl[fr], bvh, acc[fr][fn], 0, 0, 0);
                        acc[fr][fn] = __builtin_amdgcn_mfma_f32_16x16x32_f16(
                            avh[fr], bvl, acc[fr][fn], 0, 0, 0);
                    }
                }
            }
        }
    }

    // ---- epilogue: acc -> LDS (two 64-row phases) -> serial LIF scan ----
    float b1c[4];
#pragma unroll
    for (int fn = 0; fn < 4; ++fn) b1c[fn] = b1[n0 + wn + fn * 16 + l15];

    float mem = 0.f, ss = 0.f;
    const int myh = tid & 127;     // scan column for threads 0..127

    __syncthreads();               // all k-loop ds_reads done before overwrite
    // phase A: waves 0,1 (wm=0) hold C rows 0..63 = t 0..63 (fr 0..3)
    if (w < 2) {
#pragma unroll
        for (int fr = 0; fr < 4; ++fr)
#pragma unroll
            for (int r = 0; r < 4; ++r) {
                float* dst = &sm.Cs[(fr * 16 + quad * 4 + r) * CP + wn + l15];
#pragma unroll
                for (int fn = 0; fn < 4; ++fn)
                    dst[fn * 16] = acc[fr][fn][r] * ISC + b1c[fn];
            }
    }
    __syncthreads();
    if (tid < 128) {
#pragma unroll 8
        for (int t = 0; t < 64; ++t) {
            float c = sm.Cs[t * CP + myh];
            float reset = (mem > 1.0f) ? 1.0f : 0.0f;
            mem = 0.9f * mem + c - reset;
            ss += (mem > 1.0f) ? 1.0f : 0.0f;
        }
    }
    __syncthreads();
    // phase B: waves 2,3 hold C rows 64..111 (fr 0..2); scan needs 64..99
    if (w >= 2) {
#pragma unroll
        for (int fr = 0; fr < 3; ++fr)
#pragma unroll
            for (int r = 0; r < 4; ++r) {
                float* dst = &sm.Cs[(fr * 16 + quad * 4 + r) * CP + wn + l15];
#pragma unroll
                for (int fn = 0; fn < 4; ++fn)
                    dst[fn * 16] = acc[fr][fn][r] * ISC + b1c[fn];
            }
    }
    __syncthreads();
    if (tid < 128) {
#pragma unroll 6
        for (int t = 0; t < 36; ++t) {   // t global 64..99
            float c = sm.Cs[t * CP + myh];
            float reset = (mem > 1.0f) ? 1.0f : 0.0f;
            mem = 0.9f * mem + c - reset;
            ss += (mem > 1.0f) ? 1.0f : 0.0f;
        }
        // ---- FC2: logits[b][c] += sum_h ss * W2[c][h] ----
#pragma unroll
        for (int c = 0; c < C_; ++c) {
            float v = ss * W2[c * H_ + n0 + myh];
#pragma unroll
            for (int off = 32; off; off >>= 1) v += __shfl_down(v, off, 64);
            if (lane == 0) atomicAdd(&logits[b * C_ + c], v);
        }
    }
}

extern "C" void kernel_launch(void* const* d_in, const int* in_sizes, int n_in,
                              void* d_out, int out_size, void* d_ws, size_t ws_size,
                              hipStream_t stream) {
    const float* x  = (const float*)d_in[0];
    const float* W1 = (const float*)d_in[1];
    const float* b1 = (const float*)d_in[2];
    const float* W2 = (const float*)d_in[3];
    const float* b2 = (const float*)d_in[4];
    float* out = (float*)d_out;

    _Float16* Wsp = (_Float16*)d_ws;   // [1024][1024] f16 = 2 MB

    hipLaunchKernelGGL(split_w, dim3(H_ * 64 / 256), dim3(256), 0, stream,
                       W1, b2, Wsp, out);
    hipLaunchKernelGGL(snn_one, dim3(B_ * 8), dim3(256), 0, stream,
                       x, Wsp, b1, W2, out);
}

// Round 10
// 206.865 us; speedup vs baseline: 1.6025x; 1.6025x over previous
//
#include <hip/hip_runtime.h>

// SNN direction decoder — single fused kernel: in-LDS f32->f16 hi/lo split +
// MFMA GEMM + LIF scan + FC2.  B=256, T=100, I=512, H=1024, C=8.
// fp32 GEMM as 3-term f16 GEMM: xh*wh + xh*wl + xl*wh (scaled 2^6 / 2^-12).
// W pre-split [wh|wl] (2 MB ws, L2-resident); x split inside snn_one at
// LDS-write time with coalesced loads. A k-tile kt+1 prefetched into a
// register double-buffer right after barrier-1, overlapping B's L2 fetch and
// the A-convert VALU.
// R10: kt loop FULLY UNROLLED — R9's fA[cb] with runtime cb was a
// dynamically-indexed local array -> scratch spill (471 MB HBM writes).
// Unrolling makes cb compile-time so fA stays in VGPRs.

#define B_   256
#define T_   100
#define I_   512
#define H_   1024
#define C_   8
#define M_   (B_ * T_)        // 25600
#define SC   64.0f            // 2^6 pre-scale
#define ISC  (1.0f / 4096.0f) // 2^-12 epilogue un-scale
#define CP   132              // Cs row pitch (floats)

typedef _Float16 half8 __attribute__((ext_vector_type(8)));
typedef __fp16 fp16x2 __attribute__((ext_vector_type(2)));  // pkrtz native type
typedef float floatx4 __attribute__((ext_vector_type(4)));

__device__ __forceinline__ void ld_g2l(const _Float16* g, _Float16* l) {
    __builtin_amdgcn_global_load_lds(
        (const __attribute__((address_space(1))) void*)g,
        (__attribute__((address_space(3))) void*)l, 16, 0, 0);
}

__device__ __forceinline__ half8 pk_hi(float4 f0, float4 f1) {
    fp16x2 p0 = __builtin_amdgcn_cvt_pkrtz(f0.x * SC, f0.y * SC);
    fp16x2 p1 = __builtin_amdgcn_cvt_pkrtz(f0.z * SC, f0.w * SC);
    fp16x2 p2 = __builtin_amdgcn_cvt_pkrtz(f1.x * SC, f1.y * SC);
    fp16x2 p3 = __builtin_amdgcn_cvt_pkrtz(f1.z * SC, f1.w * SC);
    half8 h;
    h[0] = (_Float16)p0[0]; h[1] = (_Float16)p0[1];
    h[2] = (_Float16)p1[0]; h[3] = (_Float16)p1[1];
    h[4] = (_Float16)p2[0]; h[5] = (_Float16)p2[1];
    h[6] = (_Float16)p3[0]; h[7] = (_Float16)p3[1];
    return h;
}

// W1[H][512] fp32 -> Wsp[H][wh(512)|wl(512)] f16; also logits init.
__global__ void __launch_bounds__(256)
split_w(const float* __restrict__ W1, const float* __restrict__ b2,
        _Float16* __restrict__ Wsp, float* __restrict__ out) {
    int g = blockIdx.x * 256 + threadIdx.x;   // H_*64 threads
    if (g < B_ * C_) out[g] = 100.0f * b2[g & (C_ - 1)];
    int h = g >> 6;
    int i0 = (g & 63) * 8;
    const float* src = W1 + (size_t)h * I_ + i0;
    float4 v0 = *(const float4*)(src);
    float4 v1 = *(const float4*)(src + 4);
    float vv[8] = {v0.x, v0.y, v0.z, v0.w, v1.x, v1.y, v1.z, v1.w};
    half8 hi = pk_hi(v0, v1);
    half8 lo;
#pragma unroll
    for (int j = 0; j < 8; ++j)
        lo[j] = (_Float16)(vv[j] * SC - (float)hi[j]);
    _Float16* r = Wsp + (size_t)h * 1024 + i0;
    *(half8*)(r) = hi;
    *(half8*)(r + 512) = lo;
}

// Fused everything. XCD-swizzled: xcd=blk&7 owns batches [32*xcd, 32*xcd+32).
__global__ void __launch_bounds__(256, 2)
snn_one(const float* __restrict__ x, const _Float16* __restrict__ Wsp,
        const float* __restrict__ b1, const float* __restrict__ W2,
        float* __restrict__ logits) {
    __shared__ union {
        struct {
            __align__(16) _Float16 Ah[128 * 64];
            __align__(16) _Float16 Al[128 * 64];
            __align__(16) _Float16 Bh[128 * 64];
            __align__(16) _Float16 Bl[128 * 64];
        } g;
        float Cs[64 * CP];
    } sm;
    const int tid = threadIdx.x;
    const int lane = tid & 63;
    const int w = tid >> 6;

    const int xcd = blockIdx.x & 7;
    const int jj = blockIdx.x >> 3;        // 0..255 per-XCD sequence
    const int b  = xcd * 32 + (jj >> 3);   // batch 0..255
    const int n0 = (jj & 7) * 128;         // h tile offset

    const int wm = (w >> 1) * 64;   // wave's 64x64 sub-tile
    const int wn = (w & 1) * 64;
    const int srow = lane >> 3;
    const int sc16 = (lane & 7) ^ srow;    // XOR swizzle (matches read side)
    const int quad = lane >> 4;
    const int l15 = lane & 15;
    const int l7 = lane & 7;

    // --- B staging (async g2l): wave w stages rows [32w,32w+32), 4 x 8 rows
    const _Float16* bg[4];
    _Float16* blh[4];
    _Float16* bll[4];
#pragma unroll
    for (int j = 0; j < 4; ++j) {
        const int r = w * 32 + j * 8 + srow;
        bg[j]  = Wsp + (size_t)(n0 + r) * 1024 + sc16 * 8;
        blh[j] = &sm.g.Bh[(w * 32 + j * 8) * 64];
        bll[j] = &sm.g.Bl[(w * 32 + j * 8) * 64];
    }

    // --- A staging (manual, coalesced): 2 threads/row, 32 contiguous f32 each
    const int arow = tid >> 1;             // tile row 0..127
    const int ac0 = (tid & 1) * 32;        // col offset within k-tile
    int ar = b * T_ + arow;                // global m row (garbage masked later)
    if (ar >= M_) ar = M_ - 1;             // clamp: no OOB on last batch
    const float* axp = x + (size_t)ar * I_ + ac0;
    const bool astage = (arow < 112);      // rows 112..127 never read (fr3 skip)
    int aoff[4];                           // swizzled LDS f16 offsets
#pragma unroll
    for (int q = 0; q < 4; ++q) {
        const int k16 = (tid & 1) * 4 + q;
        aoff[q] = arow * 64 + ((k16 ^ (arow & 7)) * 8);
    }

    floatx4 acc[4][4];
#pragma unroll
    for (int i = 0; i < 4; ++i)
#pragma unroll
        for (int q = 0; q < 4; ++q) acc[i][q] = (floatx4){0.f, 0.f, 0.f, 0.f};

    // --- A register double-buffer: preload kt=0
    float4 fA[2][8];
    if (astage) {
#pragma unroll
        for (int q = 0; q < 8; ++q) fA[0][q] = *(const float4*)(axp + q * 4);
    }

#pragma unroll
    for (int kt = 0; kt < 8; ++kt) {
        const int ko = kt * 64;
        const int cb = kt & 1;             // compile-time after unroll
        __syncthreads();
#pragma unroll
        for (int j = 0; j < 4; ++j) {
            ld_g2l(bg[j] + ko, blh[j]);          // wh tile
            ld_g2l(bg[j] + 512 + ko, bll[j]);    // wl tile
        }
        if (astage) {
            // prefetch next k-tile into the other reg-buffer (overlaps convert)
            if (kt < 7) {
#pragma unroll
                for (int q = 0; q < 8; ++q)
                    fA[cb ^ 1][q] = *(const float4*)(axp + ko + 64 + q * 4);
            }
            // convert current buffer -> LDS
#pragma unroll
            for (int q = 0; q < 4; ++q) {
                float4 g0 = fA[cb][2 * q], g1 = fA[cb][2 * q + 1];
                float vv[8] = {g0.x, g0.y, g0.z, g0.w, g1.x, g1.y, g1.z, g1.w};
                half8 hi = pk_hi(g0, g1);
                half8 lo;
#pragma unroll
                for (int e = 0; e < 8; ++e)
                    lo[e] = (_Float16)(vv[e] * SC - (float)hi[e]);
                *(half8*)&sm.g.Ah[aoff[q]] = hi;
                *(half8*)&sm.g.Al[aoff[q]] = lo;
            }
        }
        __syncthreads();
#pragma unroll
        for (int ks = 0; ks < 2; ++ks) {
            const int phys = ((ks * 4 + quad) ^ l7) * 8;
            half8 avh[4], avl[4];
#pragma unroll
            for (int fr = 0; fr < 4; ++fr) {
                if (fr < 3 || wm == 0) {
                    const int ro = (wm + fr * 16 + l15) * 64 + phys;
                    avh[fr] = *(const half8*)&sm.g.Ah[ro];
                    avl[fr] = *(const half8*)&sm.g.Al[ro];
                }
            }
#pragma unroll
            for (int fn = 0; fn < 4; ++fn) {
                const int ro = (wn + fn * 16 + l15) * 64 + phys;
                half8 bvh = *(const half8*)&sm.g.Bh[ro];
                half8 bvl = *(const half8*)&sm.g.Bl[ro];
#pragma unroll
                for (int fr = 0; fr < 4; ++fr) {
                    if (fr < 3 || wm == 0) {
                        acc[fr][fn] = __builtin_amdgcn_mfma_f32_16x16x32_f16(
                            avh[fr], bvh, acc[fr][fn], 0, 0, 0);
                        acc[fr][fn] = __builtin_amdgcn_mfma_f32_16x16x32_f16(
                            avl[fr], bvh, acc[fr][fn], 0, 0, 0);
                        acc[fr][fn] = __builtin_amdgcn_mfma_f32_16x16x32_f16(
                            avh[fr], bvl, acc[fr][fn], 0, 0, 0);
                    }
                }
            }
        }
    }

    // ---- epilogue: acc -> LDS (two 64-row phases) -> serial LIF scan ----
    float b1c[4];
#pragma unroll
    for (int fn = 0; fn < 4; ++fn) b1c[fn] = b1[n0 + wn + fn * 16 + l15];

    float mem = 0.f, ss = 0.f;
    const int myh = tid & 127;     // scan column for threads 0..127

    __syncthreads();               // all k-loop ds_reads done before overwrite
    // phase A: waves 0,1 (wm=0) hold C rows 0..63 = t 0..63 (fr 0..3)
    if (w < 2) {
#pragma unroll
        for (int fr = 0; fr < 4; ++fr)
#pragma unroll
            for (int r = 0; r < 4; ++r) {
                float* dst = &sm.Cs[(fr * 16 + quad * 4 + r) * CP + wn + l15];
#pragma unroll
                for (int fn = 0; fn < 4; ++fn)
                    dst[fn * 16] = acc[fr][fn][r] * ISC + b1c[fn];
            }
    }
    __syncthreads();
    if (tid < 128) {
#pragma unroll 8
        for (int t = 0; t < 64; ++t) {
            float c = sm.Cs[t * CP + myh];
            float reset = (mem > 1.0f) ? 1.0f : 0.0f;
            mem = 0.9f * mem + c - reset;
            ss += (mem > 1.0f) ? 1.0f : 0.0f;
        }
    }
    __syncthreads();
    // phase B: waves 2,3 hold C rows 64..111 (fr 0..2); scan needs 64..99
    if (w >= 2) {
#pragma unroll
        for (int fr = 0; fr < 3; ++fr)
#pragma unroll
            for (int r = 0; r < 4; ++r) {
                float* dst = &sm.Cs[(fr * 16 + quad * 4 + r) * CP + wn + l15];
#pragma unroll
                for (int fn = 0; fn < 4; ++fn)
                    dst[fn * 16] = acc[fr][fn][r] * ISC + b1c[fn];
            }
    }
    __syncthreads();
    if (tid < 128) {
#pragma unroll 6
        for (int t = 0; t < 36; ++t) {   // t global 64..99
            float c = sm.Cs[t * CP + myh];
            float reset = (mem > 1.0f) ? 1.0f : 0.0f;
            mem = 0.9f * mem + c - reset;
            ss += (mem > 1.0f) ? 1.0f : 0.0f;
        }
        // ---- FC2: logits[b][c] += sum_h ss * W2[c][h] ----
#pragma unroll
        for (int c = 0; c < C_; ++c) {
            float v = ss * W2[c * H_ + n0 + myh];
#pragma unroll
            for (int off = 32; off; off >>= 1) v += __shfl_down(v, off, 64);
            if (lane == 0) atomicAdd(&logits[b * C_ + c], v);
        }
    }
}

extern "C" void kernel_launch(void* const* d_in, const int* in_sizes, int n_in,
                              void* d_out, int out_size, void* d_ws, size_t ws_size,
                              hipStream_t stream) {
    const float* x  = (const float*)d_in[0];
    const float* W1 = (const float*)d_in[1];
    const float* b1 = (const float*)d_in[2];
    const float* W2 = (const float*)d_in[3];
    const float* b2 = (const float*)d_in[4];
    float* out = (float*)d_out;

    _Float16* Wsp = (_Float16*)d_ws;   // [1024][1024] f16 = 2 MB

    hipLaunchKernelGGL(split_w, dim3(H_ * 64 / 256), dim3(256), 0, stream,
                       W1, b2, Wsp, out);
    hipLaunchKernelGGL(snn_one, dim3(B_ * 8), dim3(256), 0, stream,
                       x, Wsp, b1, W2, out);
}